// Round 1
// baseline (323.551 us; speedup 1.0000x reference)
//
#include <hip/hip_runtime.h>
#include <hip/hip_bf16.h>

#define Q 8192
#define DF 384
#define DP 16
#define NDATA 40000
#define K1_ROWS 16

__device__ __constant__ float kLOG2E = 1.4426950408889634f;

// K0: mean_proj[k] = sum_d pca_mean[d] * sv[d][k]
__global__ void k0_meanproj(const float* __restrict__ mean,
                            const float* __restrict__ sv,
                            float* __restrict__ mp) {
    __shared__ float red[512];
    int t = threadIdx.x;
    int k = t & 15, s = t >> 4;   // 32 slices of the d-dimension
    float acc = 0.f;
    for (int d = s; d < DF; d += 32)
        acc = fmaf(mean[d], sv[d * DP + k], acc);
    red[t] = acc;
    __syncthreads();
    if (t < 16) {
        float v = 0.f;
        for (int s2 = 0; s2 < 32; ++s2) v += red[s2 * 16 + t];
        mp[t] = v;
    }
}

// K2: b[j] = -0.5*log2e*|ds_j|^2
__global__ void k2_dsprep(const float* __restrict__ ds, float* __restrict__ b) {
    int j = blockIdx.x * blockDim.x + threadIdx.x;
    if (j >= NDATA) return;
    const float4* r = (const float4*)(ds + (size_t)j * DP);
    float ss = 0.f;
#pragma unroll
    for (int q4 = 0; q4 < 4; ++q4) {
        float4 v = r[q4];
        ss += v.x * v.x + v.y * v.y + v.z * v.z + v.w * v.w;
    }
    b[j] = -0.5f * kLOG2E * ss;
}

// K1: project 16 feature rows -> cf (log2e-scaled bw-transformed PCA coords)
//     and qb (per-query exponent bias)
__global__ __launch_bounds__(256) void k1_project(
    const float* __restrict__ feat, const float* __restrict__ sv,
    const float* __restrict__ mp, const float* __restrict__ bw,
    const float* __restrict__ maxlen_p,
    float* __restrict__ cf, float* __restrict__ qb) {
    __shared__ float frow[K1_ROWS][DF + 4];   // +4 pad: r*388%32 = 4r -> no bank conflict
    __shared__ float gbuf[K1_ROWS][DP + 1];
    int t = threadIdx.x;
    int rowbase = blockIdx.x * K1_ROWS;

    // stage 16 contiguous rows (24 KB) as float4
    const float4* src = (const float4*)(feat + (size_t)rowbase * DF);
#pragma unroll
    for (int it = 0; it < (K1_ROWS * DF / 4) / 256; ++it) {
        int idx = it * 256 + t;
        int r = idx / (DF / 4);
        int c = idx % (DF / 4);
        float4 v = src[idx];
        frow[r][c * 4 + 0] = v.x; frow[r][c * 4 + 1] = v.y;
        frow[r][c * 4 + 2] = v.z; frow[r][c * 4 + 3] = v.w;
    }
    __syncthreads();

    int r = t >> 4, k = t & 15;
    float g = 0.f;
#pragma unroll 4
    for (int d = 0; d < DF; ++d)
        g = fmaf(frow[r][d], sv[d * DP + k], g);
    g -= mp[k];                       // centering folded into projection
    gbuf[r][k] = g;
    __syncthreads();

    // f[r][j] = (sum_k g[r][k] * bw[k][j]) / maxlen
    int j = k;
    float ml = *maxlen_p;
    float f = 0.f;
#pragma unroll
    for (int kk = 0; kk < DP; ++kk)
        f = fmaf(gbuf[r][kk], bw[kk * DP + j], f);
    f /= ml;
    cf[(size_t)(rowbase + r) * DP + j] = kLOG2E * f;
    float s2 = f * f;
#pragma unroll
    for (int o = 1; o < 16; o <<= 1)
        s2 += __shfl_xor(s2, o);
    if (j == 0) qb[rowbase + r] = -0.5f * kLOG2E * s2;
}

// K3: main pairwise loop. Each block: 256 queries x one dataset chunk.
// All threads share j -> dataset row loads are wave-uniform (s_load candidates).
__global__ __launch_bounds__(256) void k3_main(
    const float* __restrict__ cf, const float* __restrict__ ds,
    const float* __restrict__ b, float* __restrict__ partial,
    int nd, int cs) {
    int qblk = blockIdx.x % 32;
    int c = blockIdx.x / 32;
    int i = qblk * 256 + threadIdx.x;

    float q[DP];
    const float4* cfr = (const float4*)(cf + (size_t)i * DP);
#pragma unroll
    for (int v4 = 0; v4 < 4; ++v4) {
        float4 v = cfr[v4];
        q[v4 * 4 + 0] = v.x; q[v4 * 4 + 1] = v.y;
        q[v4 * 4 + 2] = v.z; q[v4 * 4 + 3] = v.w;
    }

    int j0 = c * cs;
    int j1 = min(NDATA, j0 + cs);
    float acc = 0.f;
#pragma unroll 2
    for (int j = j0; j < j1; ++j) {
        const float* dsr = ds + (size_t)j * DP;
        float e0 = b[j], e1 = 0.f;
#pragma unroll
        for (int k = 0; k < DP; k += 2) {
            e0 = fmaf(q[k],     dsr[k],     e0);
            e1 = fmaf(q[k + 1], dsr[k + 1], e1);
        }
        acc += exp2f(e0 + e1);       // native v_exp_f32
    }
    partial[(size_t)c * Q + i] = acc;
}

// K4: reduce chunks, apply norm / log / logistic tail
__global__ void k4_final(const float* __restrict__ partial,
                         const float* __restrict__ qb,
                         const float* __restrict__ norm_p,
                         float* __restrict__ out, int nd) {
    int i = blockIdx.x * blockDim.x + threadIdx.x;
    if (i >= Q) return;
    float acc = 0.f;
    for (int c = 0; c < nd; ++c) acc += partial[(size_t)c * Q + i];
    float est = (*norm_p) * (1.0f / (float)NDATA) * exp2f(qb[i]) * acc;
    float score = logf(est + 1e-38f);
    out[i] = 1.0f / (1.0f + expf(0.05f * (score - 12.0f)));
}

extern "C" void kernel_launch(void* const* d_in, const int* in_sizes, int n_in,
                              void* d_out, int out_size, void* d_ws, size_t ws_size,
                              hipStream_t stream) {
    const float* features = (const float*)d_in[0];
    const float* pca_mean = (const float*)d_in[1];
    const float* sv       = (const float*)d_in[2];
    const float* maxlen   = (const float*)d_in[3];
    const float* bw       = (const float*)d_in[4];
    const float* dataset  = (const float*)d_in[5];
    const float* norm     = (const float*)d_in[6];
    float* out = (float*)d_out;

    float* ws = (float*)d_ws;
    float* cf = ws;                       // Q*DP      = 131072 floats
    float* qb = cf + (size_t)Q * DP;      // Q         = 8192
    float* bv = qb + Q;                   // NDATA     = 40000
    float* mp = bv + NDATA;               // 16 (use 64 for alignment)
    float* partial = mp + 64;             // nd * Q

    size_t used_floats = (size_t)(partial - ws);
    int nd = 64;
    size_t avail = (ws_size > used_floats * 4)
                 ? (ws_size - used_floats * 4) / (sizeof(float) * Q) : 0;
    if ((size_t)nd > avail) nd = (int)avail;
    if (nd < 1) nd = 1;
    int cs = (NDATA + nd - 1) / nd;

    k0_meanproj<<<1, 512, 0, stream>>>(pca_mean, sv, mp);
    k2_dsprep<<<(NDATA + 255) / 256, 256, 0, stream>>>(dataset, bv);
    k1_project<<<Q / K1_ROWS, 256, 0, stream>>>(features, sv, mp, bw, maxlen, cf, qb);
    k3_main<<<32 * nd, 256, 0, stream>>>(cf, dataset, bv, partial, nd, cs);
    k4_final<<<Q / 256, 256, 0, stream>>>(partial, qb, norm, out, nd);
}

// Round 2
// 149.221 us; speedup vs baseline: 2.1683x; 2.1683x over previous
//
#include <hip/hip_runtime.h>
#include <hip/hip_bf16.h>

#define Q 8192
#define DF 384
#define DP 16
#define NDATA 40000
#define K1_BLOCKS (Q / 16)                  // 512
#define K2_BLOCKS ((NDATA + 255) / 256)     // 157
#define QB_PER_BLK 128                      // queries per k3 block (4 waves x 32)
#define NQBLK (Q / QB_PER_BLK)              // 64

typedef __attribute__((ext_vector_type(8))) short short8v;   // 8 bf16 (4 VGPR)
typedef __attribute__((ext_vector_type(4))) float f32x4;

__device__ __forceinline__ unsigned short f2bf(float x) {   // RNE round to bf16
    union { float f; unsigned int u; } c; c.f = x;
    unsigned int u = c.u;
    u += 0x7fff + ((u >> 16) & 1);
    return (unsigned short)(u >> 16);
}
__device__ __forceinline__ float bf2f(unsigned short h) {
    union { float f; unsigned int u; } c; c.u = ((unsigned int)h) << 16;
    return c.f;
}
__device__ __forceinline__ float fexp2(float x) {           // raw v_exp_f32
#if __has_builtin(__builtin_amdgcn_exp2f)
    return __builtin_amdgcn_exp2f(x);
#else
    float r; asm volatile("v_exp_f32 %0, %1" : "=v"(r) : "v"(x)); return r;
#endif
}

// ---------------------------------------------------------------------------
// K_pre: blocks [0,512): query projection -> cfb (bf16, log2e-scaled), qb.
//        blocks [512,669): dataset -> dsb (bf16), bv (per-point exponent bias).
// ---------------------------------------------------------------------------
__global__ __launch_bounds__(256) void k_pre(
    const float* __restrict__ feat, const float* __restrict__ mean,
    const float* __restrict__ sv, const float* __restrict__ bw,
    const float* __restrict__ maxlen_p, const float* __restrict__ ds,
    unsigned short* __restrict__ cfb, float* __restrict__ qb,
    unsigned short* __restrict__ dsb, float* __restrict__ bv)
{
    int t = threadIdx.x;

    if (blockIdx.x >= K1_BLOCKS) {               // ---- dataset-prep role ----
        int j = (int)(blockIdx.x - K1_BLOCKS) * 256 + t;
        if (j < NDATA) {
            const float4* r = (const float4*)(ds + (size_t)j * DP);
            unsigned int packed[8];
            float ss = 0.f;
#pragma unroll
            for (int q4 = 0; q4 < 4; ++q4) {
                float4 v = r[q4];
                unsigned short h0 = f2bf(v.x), h1 = f2bf(v.y);
                unsigned short h2 = f2bf(v.z), h3 = f2bf(v.w);
                float f0 = bf2f(h0), f1 = bf2f(h1), f2 = bf2f(h2), f3 = bf2f(h3);
                ss += f0 * f0 + f1 * f1 + f2 * f2 + f3 * f3;  // from ROUNDED values
                packed[q4 * 2 + 0] = (unsigned int)h0 | ((unsigned int)h1 << 16);
                packed[q4 * 2 + 1] = (unsigned int)h2 | ((unsigned int)h3 << 16);
            }
            bv[j] = -0.72134752044f * ss;        // -0.5*log2e*|d|^2
            uint4* dst = (uint4*)(dsb + (size_t)j * DP);
            dst[0] = make_uint4(packed[0], packed[1], packed[2], packed[3]);
            dst[1] = make_uint4(packed[4], packed[5], packed[6], packed[7]);
        }
        return;
    }

    // ---- query-projection role ----
    __shared__ float frow[16][DF + 4];
    __shared__ float svs[DF * DP];
    __shared__ float gbuf[16][DP + 1];
    int rowbase = (int)blockIdx.x * 16;

    const float4* fsrc = (const float4*)(feat + (size_t)rowbase * DF);
    const float4* msrc = (const float4*)mean;
    const float4* ssrc = (const float4*)sv;
    float4* svs4 = (float4*)svs;
#pragma unroll
    for (int it = 0; it < 6; ++it) {             // 1536 float4 each
        int idx = it * 256 + t;
        int r = idx / (DF / 4), c = idx % (DF / 4);
        float4 v = fsrc[idx];
        float4 m = msrc[c];
        frow[r][c * 4 + 0] = v.x - m.x;
        frow[r][c * 4 + 1] = v.y - m.y;
        frow[r][c * 4 + 2] = v.z - m.z;
        frow[r][c * 4 + 3] = v.w - m.w;
        svs4[idx] = ssrc[idx];                   // sv is row-major [384][16]
    }
    __syncthreads();

    int r = t >> 4, k = t & 15;
    float g = 0.f;
#pragma unroll 8
    for (int d = 0; d < DF; ++d)
        g = fmaf(frow[r][d], svs[d * DP + k], g);
    gbuf[r][k] = g;
    __syncthreads();

    float ml = *maxlen_p;
    float f = 0.f;
#pragma unroll
    for (int kk = 0; kk < DP; ++kk)
        f = fmaf(gbuf[r][kk], bw[kk * DP + k], f);
    f = f * (1.4426950408889634f / 1.0f) / ml;   // F = log2e * f / maxlen
    unsigned short h = f2bf(f);
    float fr = bf2f(h);
    cfb[(size_t)(rowbase + r) * DP + k] = h;
    float s2 = fr * fr;
#pragma unroll
    for (int o = 1; o < 16; o <<= 1) s2 += __shfl_xor(s2, o);
    if (k == 0) qb[rowbase + r] = -0.34657359028f * s2;  // -0.5*ln2*|F|^2
}

// ---------------------------------------------------------------------------
// K3: MFMA pairwise loop. Block = 4 waves x 32 query rows = 128 queries.
// Wave: two 16-row A tiles (K=16 zero-padded to 32); per 16-point j-tile:
// 1 B-frag load + 2 MFMA + 8x(add bias, exp2, accumulate).
// ---------------------------------------------------------------------------
__global__ __launch_bounds__(256) void k3_main(
    const unsigned short* __restrict__ cfb, const unsigned short* __restrict__ dsb,
    const float* __restrict__ bv, float* __restrict__ partial, int cs)
{
    int qblk = (int)blockIdx.x % NQBLK;
    int c    = (int)blockIdx.x / NQBLK;
    int w = threadIdx.x >> 6, l = threadIdx.x & 63;
    int qbase = qblk * QB_PER_BLK + w * 32;
    int half = l >> 4, col = l & 15;

    short8v a0 = (short8v)0, a1 = (short8v)0;
    if (l < 32) {   // rows m=col, k = half*8 + e  (k<16; lanes 32..63 carry k pad)
        a0 = *(const short8v*)(cfb + (size_t)(qbase + col) * DP + half * 8);
        a1 = *(const short8v*)(cfb + (size_t)(qbase + 16 + col) * DP + half * 8);
    }

    int j0 = c * cs;
    int j1 = min(NDATA, j0 + cs);
    int ntile = (j1 - j0) >> 4;

    const short8v* bp = (const short8v*)(dsb + (size_t)(j0 + col) * DP + half * 8);
    const float* bvp = bv + j0 + col;

    float sacc[2][4] = {{0.f, 0.f, 0.f, 0.f}, {0.f, 0.f, 0.f, 0.f}};
    f32x4 z = {0.f, 0.f, 0.f, 0.f};

    for (int it = 0; it < ntile; ++it) {
        short8v bfrag = (short8v)0;
        if (l < 32) bfrag = *bp;
        float bj = *bvp;
        f32x4 d0 = __builtin_amdgcn_mfma_f32_16x16x32_bf16(a0, bfrag, z, 0, 0, 0);
        f32x4 d1 = __builtin_amdgcn_mfma_f32_16x16x32_bf16(a1, bfrag, z, 0, 0, 0);
#pragma unroll
        for (int r = 0; r < 4; ++r) {
            sacc[0][r] += fexp2(d0[r] + bj);
            sacc[1][r] += fexp2(d1[r] + bj);
        }
        bp += 32;        // 16 rows * 16 bf16 = 512 B = 32 short8v
        bvp += 16;
    }

    // sum over the 16 columns (lanes sharing l>>4), then lane col==0 writes
#pragma unroll
    for (int o = 1; o < 16; o <<= 1) {
#pragma unroll
        for (int tt = 0; tt < 2; ++tt)
#pragma unroll
            for (int r = 0; r < 4; ++r)
                sacc[tt][r] += __shfl_xor(sacc[tt][r], o);
    }
    if (col == 0) {
        float* dst = partial + (size_t)c * Q + qbase;
#pragma unroll
        for (int tt = 0; tt < 2; ++tt)
#pragma unroll
            for (int r = 0; r < 4; ++r)
                dst[tt * 16 + half * 4 + r] = sacc[tt][r];
    }
}

// ---------------------------------------------------------------------------
// K4: reduce partials, apply norm / log / logistic
// ---------------------------------------------------------------------------
__global__ void k4_final(const float* __restrict__ partial,
                         const float* __restrict__ qb,
                         const float* __restrict__ norm_p,
                         float* __restrict__ out, int nd)
{
    int i = (int)blockIdx.x * blockDim.x + threadIdx.x;
    if (i >= Q) return;
    float acc = 0.f;
    for (int cc = 0; cc < nd; ++cc) acc += partial[(size_t)cc * Q + i];
    float est = (*norm_p) * (1.0f / (float)NDATA) * fexp2(qb[i]) * acc;
    float score = logf(est + 1e-38f);
    out[i] = 1.0f / (1.0f + expf(0.05f * (score - 12.0f)));
}

extern "C" void kernel_launch(void* const* d_in, const int* in_sizes, int n_in,
                              void* d_out, int out_size, void* d_ws, size_t ws_size,
                              hipStream_t stream) {
    const float* features = (const float*)d_in[0];
    const float* pca_mean = (const float*)d_in[1];
    const float* sv       = (const float*)d_in[2];
    const float* maxlen   = (const float*)d_in[3];
    const float* bw       = (const float*)d_in[4];
    const float* dataset  = (const float*)d_in[5];
    const float* norm     = (const float*)d_in[6];
    float* out = (float*)d_out;

    char* ws = (char*)d_ws;
    unsigned short* cfb = (unsigned short*)(ws);                    // 262144 B
    unsigned short* dsb = (unsigned short*)(ws + 262144);           // 1280000 B
    float* bv = (float*)(ws + 262144 + 1280000);                    // 160000 B
    float* qb = (float*)(ws + 262144 + 1280000 + 160000);           // 32768 B
    float* partial = (float*)(ws + 262144 + 1280000 + 160000 + 32768);
    size_t head = 262144 + 1280000 + 160000 + 32768;

    int nd = 50;
    size_t avail = (ws_size > head) ? (ws_size - head) / ((size_t)Q * 4) : 1;
    if ((size_t)nd > avail) nd = (int)avail;
    if (nd < 1) nd = 1;
    int tiles = NDATA / 16;                      // 2500
    int tpc = (tiles + nd - 1) / nd;
    int cs = tpc * 16;
    nd = (tiles + tpc - 1) / tpc;

    k_pre<<<K1_BLOCKS + K2_BLOCKS, 256, 0, stream>>>(
        features, pca_mean, sv, bw, maxlen, dataset, cfb, qb, dsb, bv);
    k3_main<<<NQBLK * nd, 256, 0, stream>>>(cfb, dsb, bv, partial, cs);
    k4_final<<<(Q + 255) / 256, 256, 0, stream>>>(partial, qb, norm, out, nd);
}

// Round 3
// 147.233 us; speedup vs baseline: 2.1975x; 1.0135x over previous
//
#include <hip/hip_runtime.h>
#include <hip/hip_bf16.h>

#define Q 8192
#define DF 384
#define DP 16
#define NDATA 40000
#define AUGK 32                              // augmented K (coords + bias + pad)
#define ROLEA_BLOCKS 128                     // 64 query rows each
#define ROLEB_BLOCKS ((NDATA + 255) / 256)   // 157
#define NQBLK 64                             // 8192 / 128
#define QB_PER_BLK 128                       // 4 waves x 32 rows

typedef __attribute__((ext_vector_type(8))) short short8v;   // 8 bf16
typedef __attribute__((ext_vector_type(4))) float f32x4;

__device__ __forceinline__ unsigned short f2bf(float x) {   // RNE to bf16
    union { float f; unsigned int u; } c; c.f = x;
    unsigned int u = c.u;
    u += 0x7fff + ((u >> 16) & 1);
    return (unsigned short)(u >> 16);
}
__device__ __forceinline__ float bf2f(unsigned short h) {
    union { float f; unsigned int u; } c; c.u = ((unsigned int)h) << 16;
    return c.f;
}
__device__ __forceinline__ float fexp2(float x) {
#if __has_builtin(__builtin_amdgcn_exp2f)
    return __builtin_amdgcn_exp2f(x);
#else
    float r; asm volatile("v_exp_f32 %0, %1" : "=v"(r) : "v"(x)); return r;
#endif
}

// ---------------------------------------------------------------------------
// k_pre:
//  blocks [0,128):   query rows -> cfb[q][32] bf16 (log2e-scaled coords + 1.0
//                    bias slots), qb[q] (per-query exponent bias, base-2)
//  blocks [128,285): dataset -> dsb[j][32] bf16 (coords + bias hi/lo)
// ---------------------------------------------------------------------------
__global__ __launch_bounds__(256) void k_pre(
    const float* __restrict__ feat, const float* __restrict__ mean,
    const float* __restrict__ sv, const float* __restrict__ bw,
    const float* __restrict__ maxlen_p, const float* __restrict__ ds,
    unsigned short* __restrict__ cfb, float* __restrict__ qb,
    unsigned short* __restrict__ dsb)
{
    int t = threadIdx.x;

    if (blockIdx.x >= ROLEA_BLOCKS) {            // ---- dataset role ----
        int j = (int)(blockIdx.x - ROLEA_BLOCKS) * 256 + t;
        if (j < NDATA) {
            const float4* r = (const float4*)(ds + (size_t)j * DP);
            unsigned int pk[8];
            float ss = 0.f;
#pragma unroll
            for (int q4 = 0; q4 < 4; ++q4) {
                float4 v = r[q4];
                unsigned short h0 = f2bf(v.x), h1 = f2bf(v.y);
                unsigned short h2 = f2bf(v.z), h3 = f2bf(v.w);
                float f0 = bf2f(h0), f1 = bf2f(h1), f2 = bf2f(h2), f3 = bf2f(h3);
                ss += f0 * f0 + f1 * f1 + f2 * f2 + f3 * f3;   // rounded values
                pk[q4 * 2 + 0] = (unsigned int)h0 | ((unsigned int)h1 << 16);
                pk[q4 * 2 + 1] = (unsigned int)h2 | ((unsigned int)h3 << 16);
            }
            float bj = -0.72134752044f * ss;     // -0.5*log2e*|d|^2
            unsigned short hi = f2bf(bj);
            unsigned short lo = f2bf(bj - bf2f(hi));
            uint4* dst = (uint4*)(dsb + (size_t)j * AUGK);
            dst[0] = make_uint4(pk[0], pk[1], pk[2], pk[3]);
            dst[1] = make_uint4(pk[4], pk[5], pk[6], pk[7]);
            dst[2] = make_uint4((unsigned int)hi | ((unsigned int)lo << 16), 0u, 0u, 0u);
            dst[3] = make_uint4(0u, 0u, 0u, 0u);
        }
        return;
    }

    // ---- query-projection role: rows [blockIdx*64, +64) ----
    __shared__ float Mlds[DF * DP];     // 24 KB: M'' = log2e/ml * sv . bw
    __shared__ float bwl[256];
    __shared__ float red[256];
    __shared__ float cmp[16];           // mean . sv
    __shared__ float cc[16];            // c = log2e/ml * (mean.sv).bw

    float scale = 1.4426950408889634f / (*maxlen_p);
    bwl[t] = bw[t];
    {   // partial mean.sv : 16 d-slices x 16 k
        int k = t & 15, s = t >> 4;
        float a = 0.f;
        for (int d = s; d < DF; d += 16)
            a = fmaf(mean[d], sv[d * DP + k], a);
        red[t] = a;
    }
    __syncthreads();
    if (t < 16) {
        float m = 0.f;
        for (int s = 0; s < 16; ++s) m += red[s * 16 + t];
        cmp[t] = m;
    }
    // M''[d][j] = scale * sum_k sv[d][k] * bw[k][j]
    for (int d = t; d < DF; d += 256) {
        const float4* s4 = (const float4*)(sv + (size_t)d * DP);
        float4 a0 = s4[0], a1 = s4[1], a2 = s4[2], a3 = s4[3];
        float svr[16] = {a0.x, a0.y, a0.z, a0.w, a1.x, a1.y, a1.z, a1.w,
                         a2.x, a2.y, a2.z, a2.w, a3.x, a3.y, a3.z, a3.w};
        float mrow[16];
#pragma unroll
        for (int j = 0; j < 16; ++j) {
            float m = 0.f;
#pragma unroll
            for (int k = 0; k < 16; ++k) m = fmaf(svr[k], bwl[k * 16 + j], m);
            mrow[j] = scale * m;
        }
        float4* md = (float4*)(Mlds + (size_t)d * DP);
        md[0] = make_float4(mrow[0], mrow[1], mrow[2], mrow[3]);
        md[1] = make_float4(mrow[4], mrow[5], mrow[6], mrow[7]);
        md[2] = make_float4(mrow[8], mrow[9], mrow[10], mrow[11]);
        md[3] = make_float4(mrow[12], mrow[13], mrow[14], mrow[15]);
    }
    __syncthreads();
    if (t < 16) {
        float s = 0.f;
#pragma unroll
        for (int k = 0; k < 16; ++k) s = fmaf(cmp[k], bwl[k * 16 + t], s);
        cc[t] = scale * s;
    }
    __syncthreads();

    // main: thread = (row = t>>2, d-quarter = t&3); 16 accumulators
    int row = (int)blockIdx.x * 64 + (t >> 2);
    int dsl = t & 3;
    float acc[16];
#pragma unroll
    for (int k = 0; k < 16; ++k) acc[k] = 0.f;
    const float4* fb = (const float4*)(feat + (size_t)row * DF);
    for (int c = 0; c < DF / 16; ++c) {          // 24 iters
        float4 v = fb[c * 4 + dsl];
        int dbase = c * 16 + dsl * 4;
        const float fe[4] = {v.x, v.y, v.z, v.w};
#pragma unroll
        for (int e = 0; e < 4; ++e) {
            const float4* mr = (const float4*)(Mlds + (size_t)(dbase + e) * DP);
            float4 m0 = mr[0], m1 = mr[1], m2 = mr[2], m3 = mr[3];
            acc[0]  = fmaf(fe[e], m0.x, acc[0]);  acc[1]  = fmaf(fe[e], m0.y, acc[1]);
            acc[2]  = fmaf(fe[e], m0.z, acc[2]);  acc[3]  = fmaf(fe[e], m0.w, acc[3]);
            acc[4]  = fmaf(fe[e], m1.x, acc[4]);  acc[5]  = fmaf(fe[e], m1.y, acc[5]);
            acc[6]  = fmaf(fe[e], m1.z, acc[6]);  acc[7]  = fmaf(fe[e], m1.w, acc[7]);
            acc[8]  = fmaf(fe[e], m2.x, acc[8]);  acc[9]  = fmaf(fe[e], m2.y, acc[9]);
            acc[10] = fmaf(fe[e], m2.z, acc[10]); acc[11] = fmaf(fe[e], m2.w, acc[11]);
            acc[12] = fmaf(fe[e], m3.x, acc[12]); acc[13] = fmaf(fe[e], m3.y, acc[13]);
            acc[14] = fmaf(fe[e], m3.z, acc[14]); acc[15] = fmaf(fe[e], m3.w, acc[15]);
        }
    }
#pragma unroll
    for (int k = 0; k < 16; ++k) {
        acc[k] += __shfl_xor(acc[k], 1);
        acc[k] += __shfl_xor(acc[k], 2);
    }
    if (dsl == 0) {
        unsigned int pk[16];
        float s2 = 0.f;
        unsigned short h[16];
#pragma unroll
        for (int k = 0; k < 16; ++k) {
            float f = acc[k] - cc[k];            // F_scaled = log2e/ml*(feat-mean).sv.bw
            h[k] = f2bf(f);
            float fr = bf2f(h[k]);
            s2 += fr * fr;
        }
        qb[row] = -0.34657359028f * s2;          // -0.5*ln2*|Fs|^2 = -0.5*log2e*|F|^2
#pragma unroll
        for (int p = 0; p < 8; ++p)
            pk[p] = (unsigned int)h[2 * p] | ((unsigned int)h[2 * p + 1] << 16);
        pk[8] = 0x3F803F80u;                     // bf16 {1.0, 1.0} bias slots
#pragma unroll
        for (int p = 9; p < 16; ++p) pk[p] = 0u;
        uint4* dst = (uint4*)(cfb + (size_t)row * AUGK);
        dst[0] = make_uint4(pk[0], pk[1], pk[2], pk[3]);
        dst[1] = make_uint4(pk[4], pk[5], pk[6], pk[7]);
        dst[2] = make_uint4(pk[8], pk[9], pk[10], pk[11]);
        dst[3] = make_uint4(pk[12], pk[13], pk[14], pk[15]);
    }
}

// ---------------------------------------------------------------------------
// k3: per 16-point j-tile: 1 B-load (all lanes) + 2 MFMA (bias folded into K)
//     + 8 exp2 + 8 accumulate. Block = 4 waves x 32 rows.
// ---------------------------------------------------------------------------
__global__ __launch_bounds__(256) void k3_main(
    const unsigned short* __restrict__ cfb, const unsigned short* __restrict__ dsb,
    float* __restrict__ partial, int cs)
{
    int qblk = (int)blockIdx.x % NQBLK;
    int c    = (int)blockIdx.x / NQBLK;
    int w = threadIdx.x >> 6, l = threadIdx.x & 63;
    int qbase = qblk * QB_PER_BLK + w * 32;
    int kg = l >> 4, col = l & 15;

    const short8v* ap = (const short8v*)(cfb + (size_t)(qbase + col) * AUGK + kg * 8);
    short8v a0 = ap[0];
    short8v a1 = ap[64];                         // +16 rows (16*32/8)

    int j0 = c * cs;
    int j1 = min(NDATA, j0 + cs);
    int ntile = (j1 - j0) >> 4;

    const short8v* bp = (const short8v*)(dsb + (size_t)(j0 + col) * AUGK + kg * 8);

    float sacc[2][4] = {{0.f, 0.f, 0.f, 0.f}, {0.f, 0.f, 0.f, 0.f}};
    f32x4 z = {0.f, 0.f, 0.f, 0.f};

#pragma unroll 4
    for (int it = 0; it < ntile; ++it) {
        short8v bf = bp[(size_t)it * 64];        // 16 pts * 32 bf16 / 8
        f32x4 d0 = __builtin_amdgcn_mfma_f32_16x16x32_bf16(a0, bf, z, 0, 0, 0);
        f32x4 d1 = __builtin_amdgcn_mfma_f32_16x16x32_bf16(a1, bf, z, 0, 0, 0);
#pragma unroll
        for (int r = 0; r < 4; ++r) {
            sacc[0][r] += fexp2(d0[r]);
            sacc[1][r] += fexp2(d1[r]);
        }
    }

#pragma unroll
    for (int o = 1; o < 16; o <<= 1)
#pragma unroll
        for (int tt = 0; tt < 2; ++tt)
#pragma unroll
            for (int r = 0; r < 4; ++r)
                sacc[tt][r] += __shfl_xor(sacc[tt][r], o);

    if (col == 0) {
        float* dst = partial + (size_t)c * Q + qbase;
#pragma unroll
        for (int tt = 0; tt < 2; ++tt)
#pragma unroll
            for (int r = 0; r < 4; ++r)
                dst[tt * 16 + kg * 4 + r] = sacc[tt][r];
    }
}

// ---------------------------------------------------------------------------
// k4: 8-way parallel chunk reduce per query + tail
// ---------------------------------------------------------------------------
__global__ __launch_bounds__(256) void k4_final(
    const float* __restrict__ partial, const float* __restrict__ qb,
    const float* __restrict__ norm_p, float* __restrict__ out, int nd)
{
    __shared__ float l2[8][33];
    int t = threadIdx.x;
    int ql = t & 31, sl = t >> 5;
    int q = (int)blockIdx.x * 32 + ql;
    float a = 0.f;
    for (int cc = sl; cc < nd; cc += 8) a += partial[(size_t)cc * Q + q];
    l2[sl][ql] = a;
    __syncthreads();
    if (t < 32) {
        int qq = (int)blockIdx.x * 32 + t;
        float s = 0.f;
#pragma unroll
        for (int s8 = 0; s8 < 8; ++s8) s += l2[s8][t];
        float est = (*norm_p) * (1.0f / (float)NDATA) * fexp2(qb[qq]) * s;
        float score = logf(est + 1e-38f);
        out[qq] = 1.0f / (1.0f + expf(0.05f * (score - 12.0f)));
    }
}

extern "C" void kernel_launch(void* const* d_in, const int* in_sizes, int n_in,
                              void* d_out, int out_size, void* d_ws, size_t ws_size,
                              hipStream_t stream) {
    const float* features = (const float*)d_in[0];
    const float* pca_mean = (const float*)d_in[1];
    const float* sv       = (const float*)d_in[2];
    const float* maxlen   = (const float*)d_in[3];
    const float* bw       = (const float*)d_in[4];
    const float* dataset  = (const float*)d_in[5];
    const float* norm     = (const float*)d_in[6];
    float* out = (float*)d_out;

    char* ws = (char*)d_ws;
    unsigned short* cfb = (unsigned short*)(ws);                 // 8192*32*2 = 524288
    unsigned short* dsb = (unsigned short*)(ws + 524288);        // 40000*32*2 = 2560000
    float* qb = (float*)(ws + 524288 + 2560000);                 // 32768
    float* partial = (float*)(ws + 524288 + 2560000 + 32768);
    size_t head = 524288 + 2560000 + 32768;

    int nd = 32;
    size_t avail = (ws_size > head) ? (ws_size - head) / ((size_t)Q * 4) : 1;
    if ((size_t)nd > avail) nd = (int)avail;
    if (nd < 1) nd = 1;
    int tiles = NDATA / 16;                      // 2500
    int tpc = (tiles + nd - 1) / nd;
    int cs = tpc * 16;
    nd = (tiles + tpc - 1) / tpc;

    k_pre<<<ROLEA_BLOCKS + ROLEB_BLOCKS, 256, 0, stream>>>(
        features, pca_mean, sv, bw, maxlen, dataset, cfb, qb, dsb);
    k3_main<<<NQBLK * nd, 256, 0, stream>>>(cfb, dsb, partial, cs);
    k4_final<<<Q / 32, 256, 0, stream>>>(partial, qb, norm, out, nd);
}

// Round 4
// 128.035 us; speedup vs baseline: 2.5271x; 1.1499x over previous
//
#include <hip/hip_runtime.h>
#include <hip/hip_bf16.h>

#define Q 8192
#define DF 384
#define DP 16
#define NDATA 40000
#define AUGK 32
#define QPRE_BLOCKS 512                      // 16 query rows each
#define DPRE_BLOCKS ((NDATA + 255) / 256)    // 157
#define NQBLK 64                             // 8192 / 128
#define QB_PER_BLK 128                       // 4 waves x 32 rows
#define SCH_C 126.95703125f                  // Schraudolph exp2 bias constant
#define P23 8388608.f                        // 2^23

typedef __attribute__((ext_vector_type(8))) short short8v;   // 8 bf16
typedef __attribute__((ext_vector_type(4))) float f32x4;

__device__ __forceinline__ unsigned short f2bf(float x) {   // RNE to bf16
    union { float f; unsigned int u; } c; c.f = x;
    unsigned int u = c.u;
    u += 0x7fff + ((u >> 16) & 1);
    return (unsigned short)(u >> 16);
}
__device__ __forceinline__ float bf2f(unsigned short h) {
    union { float f; unsigned int u; } c; c.u = ((unsigned int)h) << 16;
    return c.f;
}
__device__ __forceinline__ float i2f_bits(int i) {
    union { int i; float f; } c; c.i = i; return c.f;
}
__device__ __forceinline__ float fexp2(float x) {
#if __has_builtin(__builtin_amdgcn_exp2f)
    return __builtin_amdgcn_exp2f(x);
#else
    float r; asm volatile("v_exp_f32 %0, %1" : "=v"(r) : "v"(x)); return r;
#endif
}

// ---------------------------------------------------------------------------
// k_mm (1 block, 384 threads): M2[d][k] = 2^23*log2e/ml * (sv.bw)[d][k]  (fp32)
//                              cc[k]    = 2^23*log2e/ml * ((mean.sv).bw)[k]
// ---------------------------------------------------------------------------
__global__ __launch_bounds__(384) void k_mm(
    const float* __restrict__ mean, const float* __restrict__ sv,
    const float* __restrict__ bw, const float* __restrict__ maxlen_p,
    float* __restrict__ M2, float* __restrict__ cc)
{
    __shared__ float bwl[256];
    __shared__ float red[384];
    __shared__ float cmps[16];
    int t = threadIdx.x;
    if (t < 256) bwl[t] = bw[t];
    {   // mean.sv partials: 24 slices x 16 k
        int k = t & 15, s = t >> 4;
        float a = 0.f;
        for (int d = s; d < DF; d += 24)
            a = fmaf(mean[d], sv[d * DP + k], a);
        red[t] = a;
    }
    __syncthreads();
    float scale = P23 * 1.4426950408889634f / (*maxlen_p);
    {   // M2 row d = t
        const float4* s4 = (const float4*)(sv + (size_t)t * DP);
        float4 a0 = s4[0], a1 = s4[1], a2 = s4[2], a3 = s4[3];
        float svr[16] = {a0.x, a0.y, a0.z, a0.w, a1.x, a1.y, a1.z, a1.w,
                         a2.x, a2.y, a2.z, a2.w, a3.x, a3.y, a3.z, a3.w};
        float mrow[16];
#pragma unroll
        for (int j = 0; j < 16; ++j) {
            float m = 0.f;
#pragma unroll
            for (int k = 0; k < 16; ++k) m = fmaf(svr[k], bwl[k * 16 + j], m);
            mrow[j] = scale * m;
        }
        float4* md = (float4*)(M2 + (size_t)t * DP);
        md[0] = make_float4(mrow[0], mrow[1], mrow[2], mrow[3]);
        md[1] = make_float4(mrow[4], mrow[5], mrow[6], mrow[7]);
        md[2] = make_float4(mrow[8], mrow[9], mrow[10], mrow[11]);
        md[3] = make_float4(mrow[12], mrow[13], mrow[14], mrow[15]);
    }
    if (t < 16) {
        float m = 0.f;
        for (int s = 0; s < 24; ++s) m += red[s * 16 + t];
        cmps[t] = m;
    }
    __syncthreads();
    if (t < 16) {
        float s = 0.f;
#pragma unroll
        for (int k = 0; k < 16; ++k) s = fmaf(cmps[k], bwl[k * 16 + t], s);
        cc[t] = scale * s;
    }
}

// ---------------------------------------------------------------------------
// k_pre:
//  blocks [0,512):  16 query rows -> cfb[q][32] bf16: slots 0-15 = 2^23-scaled
//                   coords, 16/17 = 2^23; qb[q]
//  blocks [512,..): dataset -> dsb[j][32] bf16: coords + v=(C-0.72135|d|^2) hi/lo
// ---------------------------------------------------------------------------
__global__ __launch_bounds__(256) void k_pre(
    const float* __restrict__ feat, const float* __restrict__ ds,
    const float* __restrict__ M2, const float* __restrict__ cc,
    unsigned short* __restrict__ cfb, float* __restrict__ qb,
    unsigned short* __restrict__ dsb)
{
    int t = threadIdx.x;

    if (blockIdx.x >= QPRE_BLOCKS) {             // ---- dataset role ----
        int j = (int)(blockIdx.x - QPRE_BLOCKS) * 256 + t;
        if (j < NDATA) {
            const float4* r = (const float4*)(ds + (size_t)j * DP);
            unsigned int pk[8];
            float ss = 0.f;
#pragma unroll
            for (int q4 = 0; q4 < 4; ++q4) {
                float4 v = r[q4];
                unsigned short h0 = f2bf(v.x), h1 = f2bf(v.y);
                unsigned short h2 = f2bf(v.z), h3 = f2bf(v.w);
                float f0 = bf2f(h0), f1 = bf2f(h1), f2 = bf2f(h2), f3 = bf2f(h3);
                ss += f0 * f0 + f1 * f1 + f2 * f2 + f3 * f3;   // rounded values
                pk[q4 * 2 + 0] = (unsigned int)h0 | ((unsigned int)h1 << 16);
                pk[q4 * 2 + 1] = (unsigned int)h2 | ((unsigned int)h3 << 16);
            }
            float v = fmaf(ss, -0.72134752044f, SCH_C);  // C - 0.5*log2e*|d|^2
            unsigned short hi = f2bf(v);
            unsigned short lo = f2bf(v - bf2f(hi));
            uint4* dst = (uint4*)(dsb + (size_t)j * AUGK);
            dst[0] = make_uint4(pk[0], pk[1], pk[2], pk[3]);
            dst[1] = make_uint4(pk[4], pk[5], pk[6], pk[7]);
            dst[2] = make_uint4((unsigned int)hi | ((unsigned int)lo << 16), 0u, 0u, 0u);
            dst[3] = make_uint4(0u, 0u, 0u, 0u);
        }
        return;
    }

    // ---- query role: rows [blockIdx*16, +16) ----
    __shared__ __align__(16) float m2l[DF * 20];    // [384][20] pad: 2-way max
    __shared__ float ccl[16];
    const float4* m2g = (const float4*)M2;
#pragma unroll
    for (int it = 0; it < 6; ++it) {
        int i = it * 256 + t;
        int d = i >> 2, qq = i & 3;
        *(float4*)(m2l + d * 20 + qq * 4) = m2g[i];
    }
    if (t < 16) ccl[t] = cc[t];
    __syncthreads();

    int r = t >> 4, s = t & 15;
    int row = (int)blockIdx.x * 16 + r;
    float acc[16];
#pragma unroll
    for (int k = 0; k < 16; ++k) acc[k] = 0.f;
    const float* fr = feat + (size_t)row * DF;
#pragma unroll 4
    for (int c = 0; c < 24; ++c) {
        int d = s + (c << 4);
        float fv = fr[d];
        const float4* mr = (const float4*)(m2l + d * 20);
        float4 m0 = mr[0], m1 = mr[1], m2 = mr[2], m3 = mr[3];
        acc[0]  = fmaf(fv, m0.x, acc[0]);  acc[1]  = fmaf(fv, m0.y, acc[1]);
        acc[2]  = fmaf(fv, m0.z, acc[2]);  acc[3]  = fmaf(fv, m0.w, acc[3]);
        acc[4]  = fmaf(fv, m1.x, acc[4]);  acc[5]  = fmaf(fv, m1.y, acc[5]);
        acc[6]  = fmaf(fv, m1.z, acc[6]);  acc[7]  = fmaf(fv, m1.w, acc[7]);
        acc[8]  = fmaf(fv, m2.x, acc[8]);  acc[9]  = fmaf(fv, m2.y, acc[9]);
        acc[10] = fmaf(fv, m2.z, acc[10]); acc[11] = fmaf(fv, m2.w, acc[11]);
        acc[12] = fmaf(fv, m3.x, acc[12]); acc[13] = fmaf(fv, m3.y, acc[13]);
        acc[14] = fmaf(fv, m3.z, acc[14]); acc[15] = fmaf(fv, m3.w, acc[15]);
    }
#pragma unroll
    for (int k = 0; k < 16; ++k) {
        acc[k] += __shfl_xor(acc[k], 1);
        acc[k] += __shfl_xor(acc[k], 2);
        acc[k] += __shfl_xor(acc[k], 4);
        acc[k] += __shfl_xor(acc[k], 8);
    }
    if (s == 0) {
        unsigned int pk[16];
        unsigned short h[16];
        float s2 = 0.f;
#pragma unroll
        for (int k = 0; k < 16; ++k) {
            float f = acc[k] - ccl[k];           // 2^23 * log2e/ml * proj
            h[k] = f2bf(f);
            float fr2 = bf2f(h[k]) * (1.f / P23);
            s2 += fr2 * fr2;
        }
        qb[row] = -0.34657359028f * s2;          // -0.5*ln2*|Fs|^2
#pragma unroll
        for (int p = 0; p < 8; ++p)
            pk[p] = (unsigned int)h[2 * p] | ((unsigned int)h[2 * p + 1] << 16);
        pk[8] = 0x4B004B00u;                     // bf16 {2^23, 2^23}
#pragma unroll
        for (int p = 9; p < 16; ++p) pk[p] = 0u;
        uint4* dst = (uint4*)(cfb + (size_t)row * AUGK);
        dst[0] = make_uint4(pk[0], pk[1], pk[2], pk[3]);
        dst[1] = make_uint4(pk[4], pk[5], pk[6], pk[7]);
        dst[2] = make_uint4(pk[8], pk[9], pk[10], pk[11]);
        dst[3] = make_uint4(pk[12], pk[13], pk[14], pk[15]);
    }
}

// ---------------------------------------------------------------------------
// k3: MFMA outputs t = 2^23*(x + C) directly; epilogue = cvt_i32 + add.
// ---------------------------------------------------------------------------
__global__ __launch_bounds__(256) void k3_main(
    const unsigned short* __restrict__ cfb, const unsigned short* __restrict__ dsb,
    float* __restrict__ partial, int cs)
{
    int qblk = (int)blockIdx.x % NQBLK;
    int c    = (int)blockIdx.x / NQBLK;
    int w = threadIdx.x >> 6, l = threadIdx.x & 63;
    int qbase = qblk * QB_PER_BLK + w * 32;
    int kg = l >> 4, col = l & 15;

    const short8v* ap = (const short8v*)(cfb + (size_t)(qbase + col) * AUGK + kg * 8);
    short8v a0 = ap[0];
    short8v a1 = ap[64];                         // +16 rows

    int j0 = c * cs;
    int j1 = min(NDATA, j0 + cs);
    int ntile = (j1 - j0) >> 4;

    const short8v* bp = (const short8v*)(dsb + (size_t)(j0 + col) * AUGK + kg * 8);

    float sacc[2][4] = {{0.f, 0.f, 0.f, 0.f}, {0.f, 0.f, 0.f, 0.f}};
    f32x4 z = {0.f, 0.f, 0.f, 0.f};

#pragma unroll 4
    for (int it = 0; it < ntile; ++it) {
        short8v bf = bp[(size_t)it * 64];
        f32x4 d0 = __builtin_amdgcn_mfma_f32_16x16x32_bf16(a0, bf, z, 0, 0, 0);
        f32x4 d1 = __builtin_amdgcn_mfma_f32_16x16x32_bf16(a1, bf, z, 0, 0, 0);
#pragma unroll
        for (int r = 0; r < 4; ++r) {
            sacc[0][r] += i2f_bits((int)d0[r]);  // Schraudolph exp2
            sacc[1][r] += i2f_bits((int)d1[r]);
        }
    }

#pragma unroll
    for (int o = 1; o < 16; o <<= 1)
#pragma unroll
        for (int tt = 0; tt < 2; ++tt)
#pragma unroll
            for (int r = 0; r < 4; ++r)
                sacc[tt][r] += __shfl_xor(sacc[tt][r], o);

    if (col == 0) {
        float* dst = partial + (size_t)c * Q + qbase;
#pragma unroll
        for (int tt = 0; tt < 2; ++tt)
#pragma unroll
            for (int r = 0; r < 4; ++r)
                dst[tt * 16 + kg * 4 + r] = sacc[tt][r];
    }
}

// ---------------------------------------------------------------------------
// k4: reduce chunks + tail
// ---------------------------------------------------------------------------
__global__ __launch_bounds__(256) void k4_final(
    const float* __restrict__ partial, const float* __restrict__ qb,
    const float* __restrict__ norm_p, float* __restrict__ out, int nd)
{
    __shared__ float l2[8][33];
    int t = threadIdx.x;
    int ql = t & 31, sl = t >> 5;
    int q = (int)blockIdx.x * 32 + ql;
    float a = 0.f;
    for (int cc = sl; cc < nd; cc += 8) a += partial[(size_t)cc * Q + q];
    l2[sl][ql] = a;
    __syncthreads();
    if (t < 32) {
        int qq = (int)blockIdx.x * 32 + t;
        float s = 0.f;
#pragma unroll
        for (int s8 = 0; s8 < 8; ++s8) s += l2[s8][t];
        float est = (*norm_p) * (1.0f / (float)NDATA) * fexp2(qb[qq]) * s;
        float score = logf(est + 1e-38f);
        out[qq] = 1.0f / (1.0f + expf(0.05f * (score - 12.0f)));
    }
}

extern "C" void kernel_launch(void* const* d_in, const int* in_sizes, int n_in,
                              void* d_out, int out_size, void* d_ws, size_t ws_size,
                              hipStream_t stream) {
    const float* features = (const float*)d_in[0];
    const float* pca_mean = (const float*)d_in[1];
    const float* sv       = (const float*)d_in[2];
    const float* maxlen   = (const float*)d_in[3];
    const float* bw       = (const float*)d_in[4];
    const float* dataset  = (const float*)d_in[5];
    const float* norm     = (const float*)d_in[6];
    float* out = (float*)d_out;

    char* ws = (char*)d_ws;
    unsigned short* cfb = (unsigned short*)(ws);                 // 524288 B
    unsigned short* dsb = (unsigned short*)(ws + 524288);        // 2560000 B
    float* qb = (float*)(ws + 524288 + 2560000);                 // 32768 B
    float* M2 = (float*)(ws + 524288 + 2560000 + 32768);         // 24576 B
    float* cc = (float*)(ws + 524288 + 2560000 + 32768 + 24576); // 256 B
    float* partial = (float*)(ws + 524288 + 2560000 + 32768 + 24576 + 256);
    size_t head = 524288 + 2560000 + 32768 + 24576 + 256;

    int nd = 32;
    size_t avail = (ws_size > head) ? (ws_size - head) / ((size_t)Q * 4) : 1;
    if ((size_t)nd > avail) nd = (int)avail;
    if (nd < 1) nd = 1;
    int tiles = NDATA / 16;                      // 2500
    int tpc = (tiles + nd - 1) / nd;
    int cs = tpc * 16;
    nd = (tiles + tpc - 1) / tpc;

    k_mm<<<1, 384, 0, stream>>>(pca_mean, sv, bw, maxlen, M2, cc);
    k_pre<<<QPRE_BLOCKS + DPRE_BLOCKS, 256, 0, stream>>>(
        features, dataset, M2, cc, cfb, qb, dsb);
    k3_main<<<NQBLK * nd, 256, 0, stream>>>(cfb, dsb, partial, cs);
    k4_final<<<Q / 32, 256, 0, stream>>>(partial, qb, norm, out, nd);
}